// Round 15
// baseline (100.195 us; speedup 1.0000x reference)
//
#include <hip/hip_runtime.h>
#include <hip/hip_bf16.h>
#include <math.h>

typedef float f4 __attribute__((ext_vector_type(4)));
typedef float f32x4 __attribute__((ext_vector_type(4)));
typedef short s8v __attribute__((ext_vector_type(8)));
typedef unsigned short u16;
typedef u16 u16x4 __attribute__((ext_vector_type(4)));
typedef u16 u16x8 __attribute__((ext_vector_type(8)));

#define TT 2048
#define CC 768
#define HH 64
#define NB 8
#define NBT (NB * TT)
#define NQ (NBT * HH)
#define QSCALE 0.18033688011112042f   // 0.125 * log2(e): softmax in base-2

__device__ __forceinline__ u16 f2bf(float f) {
  unsigned u = __float_as_uint(f);
  u = (u + 0x7fffu + ((u >> 16) & 1u)) >> 16;
  return (u16)u;
}
__device__ __forceinline__ float bf2f(u16 v) {
  return __uint_as_float(((unsigned)v) << 16);
}
__device__ __forceinline__ u16x4 pack4(f32x4 v) {
  union { u16x4 u; __hip_bfloat162 h[2]; } r;
  r.h[0] = __float22bfloat162_rn(make_float2(v[0], v[1]));
  r.h[1] = __float22bfloat162_rn(make_float2(v[2], v[3]));
  return r.u;
}
__device__ __forceinline__ s8v pack8(f4 lo, f4 hi) {
  union { s8v s; __hip_bfloat162 h[4]; } r;
  r.h[0] = __float22bfloat162_rn(make_float2(lo.x, lo.y));
  r.h[1] = __float22bfloat162_rn(make_float2(lo.z, lo.w));
  r.h[2] = __float22bfloat162_rn(make_float2(hi.x, hi.y));
  r.h[3] = __float22bfloat162_rn(make_float2(hi.z, hi.w));
  return r.s;
}

#define MFMA16(a, b, c) __builtin_amdgcn_mfma_f32_16x16x32_bf16(a, b, c, 0, 0, 0)

// ---------------------------------------------------------------------------
// Kernel 0: W -> bf16 transposed via LDS tile transpose. wt[c][kc],
// c: 0..63 q, 64..127 k, 128..191 v.
// ---------------------------------------------------------------------------
__global__ __launch_bounds__(256) void prep_w(
    const float* __restrict__ Wk, const float* __restrict__ Wq,
    const float* __restrict__ Wv, u16* __restrict__ wt) {
  __shared__ float ls[64][72];
  const int tid = threadIdx.x;
  const int m = blockIdx.x / 12, kt = blockIdx.x % 12, k0 = kt * 64;
  const float* Wm = (m == 0) ? Wq : (m == 1) ? Wk : Wv;
#pragma unroll
  for (int p = 0; p < 4; ++p) {
    int k = p * 16 + (tid >> 4), h4 = (tid & 15) * 4;
    f4 v = *(const f4*)(Wm + (size_t)(k0 + k) * HH + h4);
    *(f4*)&ls[k][h4] = v;
  }
  __syncthreads();
#pragma unroll
  for (int p = 0; p < 2; ++p) {
    int c = p * 32 + (tid >> 3), slot = tid & 7;
    u16x8 o;
#pragma unroll
    for (int j = 0; j < 8; ++j) o[j] = f2bf(ls[slot * 8 + j][c]);
    *(u16x8*)(wt + (size_t)(m * 64 + c) * CC + k0 + slot * 8) = o;
  }
}

// ---------------------------------------------------------------------------
// Kernel 1: QKV projection (R14-proven, byte-identical). 512 threads (8
// waves: 2 row-groups x 4 col-groups, 3 accs/wave), 16 waves/CU.
// x and W staged via global_load_lds (pre-swizzled source, linear dest).
// LDS: x 2x8KB @0, W 2x24KB @16384.
// ---------------------------------------------------------------------------
__global__ __launch_bounds__(512) void qkv_proj(
    const float* __restrict__ x, const u16* __restrict__ wt,
    u16* __restrict__ qb, u16* __restrict__ kb, u16* __restrict__ vt) {
  __shared__ char lds[65536];
  const int tid = threadIdx.x;
  const int w = tid >> 6, lane = tid & 63;
  const int g = lane >> 4, t16 = lane & 15;
  const int rg = w >> 2, cg = w & 3;
  const int row0 = blockIdx.x * 32;

  auto stage = [&](int buf, int kt) {   // 4 gload_lds per thread
    const int k0 = kt * 64;
    {  // x tile: 512 16B-units, 1 per thread
      int row = tid >> 4;
      int logical = ((tid & 15) * 16) ^ ((row & 7) << 5);
      const float* src = x + (size_t)(row0 + row) * CC + k0 + (logical >> 2);
      char* dst = lds + buf * 8192 + tid * 16;
      __builtin_amdgcn_global_load_lds((const unsigned int*)src,
                                       (unsigned int*)dst, 16, 0, 0);
    }
#pragma unroll
    for (int n = 0; n < 3; ++n) {       // W tile: 1536 units, 3 per thread
      int u = n * 512 + tid;
      int col = u >> 3;
      int logical = ((u & 7) * 16) ^ ((col & 7) << 4);
      const u16* src = wt + (size_t)col * CC + k0 + (logical >> 1);
      char* dst = lds + 16384 + buf * 24576 + n * 8192 + tid * 16;
      __builtin_amdgcn_global_load_lds((const unsigned int*)src,
                                       (unsigned int*)dst, 16, 0, 0);
    }
  };

  f32x4 zz = {0.f, 0.f, 0.f, 0.f};
  f32x4 acc[3];
#pragma unroll
  for (int cf = 0; cf < 3; ++cf) acc[cf] = zz;

  stage(0, 0);
  asm volatile("s_waitcnt vmcnt(0)" ::: "memory");
  __syncthreads();

  for (int kt = 0; kt < 12; ++kt) {
    const int buf = kt & 1;
    if (kt < 11) stage(buf ^ 1, kt + 1);

    const int row = rg * 16 + t16;
    s8v a[2];
#pragma unroll
    for (int ks = 0; ks < 2; ++ks) {
      int off = buf * 8192 + row * 256 +
                ((ks * 128 + g * 32) ^ ((row & 7) << 5));
      f4 lo = *(const f4*)(lds + off);
      f4 hi = *(const f4*)(lds + off + 16);
      a[ks] = pack8(lo, hi);
    }
#pragma unroll
    for (int cf = 0; cf < 3; ++cf) {
      int col = cg * 48 + cf * 16 + t16;
      int wo = 16384 + buf * 24576 + col * 128;
#pragma unroll
      for (int ks = 0; ks < 2; ++ks) {
        s8v b = *(const s8v*)(lds + wo +
                              ((ks * 64 + g * 16) ^ ((col & 7) << 4)));
        acc[cf] = MFMA16(a[ks], b, acc[cf]);
      }
    }

    asm volatile("s_waitcnt vmcnt(0)" ::: "memory");
    __syncthreads();
  }

  // epilogue: D row = g*4+r, col = t16 (m89-verified layout)
  const int rb = row0 + rg * 16 + g * 4;
#pragma unroll
  for (int cf = 0; cf < 3; ++cf) {
    int col = cg * 48 + cf * 16 + t16;
    int m = col >> 6, h = col & 63;
    if (m == 0) {
#pragma unroll
      for (int r = 0; r < 4; ++r)
        qb[(size_t)(rb + r) * HH + h] = f2bf(acc[cf][r] * QSCALE);
    } else if (m == 1) {
#pragma unroll
      for (int r = 0; r < 4; ++r)
        kb[(size_t)(rb + r) * HH + h] = f2bf(acc[cf][r]);
    } else {
      int bbi = rb >> 11;
      u16x4 pk = pack4(acc[cf]);
      *(u16x4*)(vt + (size_t)(bbi * 64 + h) * TT + (rb & 2047)) = pk;
    }
  }
}

// ---------------------------------------------------------------------------
// Kernel 2: flash attention (R7-proven, byte-identical). 8 waves/block,
// Q-block 128 rows (wave=16 rows, swapped QK^T: lane owns q-row). KV tile 64
// staged once in LDS (K + V^T), TRIPLE-buffered, depth-2 prefetch, counted
// vmcnt(2). Defer-max THR=8. LDS: K 3x8KB, V 3x8KB, P 8x2KB = 64KB.
// ---------------------------------------------------------------------------
__global__ __launch_bounds__(512) void attn(
    const u16* __restrict__ qb, const u16* __restrict__ kb,
    const u16* __restrict__ vt, float* __restrict__ out,
    float* __restrict__ ml, u16* __restrict__ ob, int CH, int CHL) {
  __shared__ char lds[65536];
  const int tid = threadIdx.x;
  const int w = tid >> 6, lane = tid & 63;
  const int g = lane >> 4, t16 = lane & 15;
  const int bid = blockIdx.x;
  const int b = bid & 7;
  int J = bid >> 3;

  int q = 15;                           // heavy-first job decode
#pragma unroll 16
  for (int i = 0; i < 16; ++i) {
    int nc_q = (q * 128 + 128 + CH - 1) >> CHL;
    if (J < nc_q) break;
    J -= nc_q;
    --q;
  }
  const int qt = q, ch = J;
  const int q0 = qt * 128;
  const int nc = (q0 + 128 + CH - 1) >> CHL;
  const int kv_lo = ch << CHL;
  const int kv_hi = min(kv_lo + CH, q0 + 128);
  const int nt = (kv_hi - kv_lo) >> 6;
  const int q0w = q0 + w * 16;
  const size_t bT = (size_t)b * TT;
  const int wbase = 49152 + w * 2048;

  // Q as B-fragment (pre-scaled): lane col q = q0w+t16
  s8v qf[2];
#pragma unroll
  for (int s = 0; s < 2; ++s)
    qf[s] = *(const s8v*)(qb + (bT + q0w + t16) * HH + s * 32 + g * 8);

  auto stage = [&](int buf, int kv0) {
    int row = tid >> 3, slot = tid & 7;
    int co = (slot ^ (row & 7)) << 3;
    const u16* sK = kb + (bT + kv0 + row) * HH + co;
    const u16* sV = vt + (size_t)(b * 64 + row) * TT + kv0 + co;
    char* dK = lds + buf * 8192 + w * 1024;
    char* dV = lds + 24576 + buf * 8192 + w * 1024;
    __builtin_amdgcn_global_load_lds((const unsigned int*)sK,
                                     (unsigned int*)dK, 16, 0, 0);
    __builtin_amdgcn_global_load_lds((const unsigned int*)sV,
                                     (unsigned int*)dV, 16, 0, 0);
  };

  float m = -INFINITY, l = 0.f;
  f32x4 zz = {0.f, 0.f, 0.f, 0.f};
  f32x4 oa[4] = {zz, zz, zz, zz};

  stage(0, kv_lo);
  if (nt > 1) stage(1, kv_lo + 64);

  for (int t = 0; t < nt; ++t) {
    const int kv0 = kv_lo + t * 64;
    const int buf = t % 3;
    if (t + 1 < nt) {
      asm volatile("s_waitcnt vmcnt(2)" ::: "memory");
    } else {
      asm volatile("s_waitcnt vmcnt(0)" ::: "memory");
    }
    __syncthreads();   // publishes stage(t); gates buffer reuse

    if (kv0 <= q0w + 15) {              // wave-uniform: skip fully-masked
      f32x4 sa[4] = {zz, zz, zz, zz};
#pragma unroll
      for (int c = 0; c < 4; ++c) {
        int row = c * 16 + t16;
        s8v k0_ = *(const s8v*)(lds + buf * 8192 +
                                ((row * 128 + g * 16) ^ ((row & 7) << 4)));
        s8v k1_ = *(const s8v*)(lds + buf * 8192 +
                                ((row * 128 + 64 + g * 16) ^ ((row & 7) << 4)));
        sa[c] = MFMA16(k0_, qf[0], sa[c]);
        sa[c] = MFMA16(k1_, qf[1], sa[c]);
      }

      if (kv0 + 63 > q0w) {             // diagonal tile: causal mask
#pragma unroll
        for (int c = 0; c < 4; ++c)
#pragma unroll
          for (int r = 0; r < 4; ++r)
            if (kv0 + c * 16 + g * 4 + r > q0w + t16) sa[c][r] = -INFINITY;
      }

      // online softmax (base-2), defer-max THR=8
      f32x4 mm = sa[0];
#pragma unroll
      for (int c = 1; c < 4; ++c)
#pragma unroll
        for (int r = 0; r < 4; ++r) mm[r] = fmaxf(mm[r], sa[c][r]);
      float mx = fmaxf(fmaxf(mm[0], mm[1]), fmaxf(mm[2], mm[3]));
      mx = fmaxf(mx, __shfl_xor(mx, 16));
      mx = fmaxf(mx, __shfl_xor(mx, 32));
      if (!__all(mx <= m + 8.f)) {
        float mn = fmaxf(m, mx);
        float fr = exp2f(m - mn);
        m = mn;
        l *= fr;
#pragma unroll
        for (int c = 0; c < 4; ++c) oa[c] *= fr;
      }
      f32x4 ps = zz;
#pragma unroll
      for (int c = 0; c < 4; ++c)
#pragma unroll
        for (int r = 0; r < 4; ++r) {
          float p = exp2f(sa[c][r] - m);
          sa[c][r] = p;
          ps[r] += p;
        }
      float rs = (ps[0] + ps[1]) + (ps[2] + ps[3]);
      rs += __shfl_xor(rs, 16);
      rs += __shfl_xor(rs, 32);
      l += rs;

      // P -> wave-private LDS (bf16, swizzled)
#pragma unroll
      for (int c = 0; c < 4; ++c) {
        u16x4 pk = pack4(sa[c]);
        int off = wbase + ((t16 * 128 + c * 32 + g * 8) ^ ((t16 & 7) << 4));
        *(u16x4*)(lds + off) = pk;
      }
      // O^T += V^T . P^T
#pragma unroll
      for (int ks = 0; ks < 2; ++ks) {
        int poff = wbase + ((t16 * 128 + ks * 64 + g * 16) ^ ((t16 & 7) << 4));
        s8v pf = *(const s8v*)(lds + poff);
#pragma unroll
        for (int c = 0; c < 4; ++c) {
          int row = c * 16 + t16;
          s8v vf = *(const s8v*)(lds + 24576 + buf * 8192 +
                                 ((row * 128 + ks * 64 + g * 16) ^
                                  ((row & 7) << 4)));
          oa[c] = MFMA16(vf, pf, oa[c]);
        }
      }
    }

    if (t + 2 < nt) stage((t + 2) % 3, kv0 + 128);
  }

  if (nc == 1) {                        // whole causal range: direct write
    float inv = 1.0f / l;
#pragma unroll
    for (int c = 0; c < 4; ++c) {
      f4 st;
#pragma unroll
      for (int r = 0; r < 4; ++r) st[r] = oa[c][r] * inv;
      *(f4*)(out + (bT + q0w + t16) * HH + c * 16 + g * 4) = st;
    }
  } else {                              // partial: m,l + unnormalized O
    int maxnc = 1 << (11 - CHL);
    int slot = (b * 16 + qt) * maxnc + ch;
    if (g == 0) {
      ml[slot * 256 + w * 16 + t16] = m;
      ml[slot * 256 + 128 + w * 16 + t16] = l;
    }
#pragma unroll
    for (int c = 0; c < 4; ++c) {
      u16x4 pk = pack4(oa[c]);
      *(u16x4*)(ob + (size_t)slot * 8192 + (w * 16 + t16) * 64 + c * 16 +
                g * 4) = pk;
    }
  }
}

// ---------------------------------------------------------------------------
// Kernel 3: combine split-KV partials. Thread = (row, 8 h-cols).
// ---------------------------------------------------------------------------
__global__ __launch_bounds__(256) void combine(
    const float* __restrict__ ml, const u16* __restrict__ ob,
    float* __restrict__ out, int CH, int CHL) {
  int gid = blockIdx.x * 256 + threadIdx.x;   // 131072
  int r = gid >> 3, c8 = (gid & 7) << 3;
  int b = r >> 11, qrow = r & 2047, qt = qrow >> 7, qi = qrow & 127;
  int nc = (qt * 128 + 128 + CH - 1) >> CHL;
  if (nc < 2) return;                          // attn wrote these directly
  int maxnc = 1 << (11 - CHL);
  int s0 = (b * 16 + qt) * maxnc;
  float M = -INFINITY;
  for (int ch = 0; ch < nc; ++ch) M = fmaxf(M, ml[(s0 + ch) * 256 + qi]);
  float L = 0.f;
  float o[8] = {0, 0, 0, 0, 0, 0, 0, 0};
  for (int ch = 0; ch < nc; ++ch) {
    float wgt = exp2f(ml[(s0 + ch) * 256 + qi] - M);
    L += ml[(s0 + ch) * 256 + 128 + qi] * wgt;
    const u16x4* src =
        (const u16x4*)(ob + (size_t)(s0 + ch) * 8192 + qi * 64 + c8);
    u16x4 a = src[0], bv = src[1];
#pragma unroll
    for (int j = 0; j < 4; ++j) {
      o[j] += wgt * bf2f(a[j]);
      o[4 + j] += wgt * bf2f(bv[j]);
    }
  }
  float inv = 1.0f / L;
  f4 s1, s2;
#pragma unroll
  for (int j = 0; j < 4; ++j) { s1[j] = o[j] * inv; s2[j] = o[4 + j] * inv; }
  *(f4*)(out + (size_t)r * HH + c8) = s1;
  *(f4*)(out + (size_t)r * HH + c8 + 4) = s2;
}

extern "C" void kernel_launch(void* const* d_in, const int* in_sizes, int n_in,
                              void* d_out, int out_size, void* d_ws, size_t ws_size,
                              hipStream_t stream) {
  (void)in_sizes; (void)n_in; (void)out_size;
  const float* x  = (const float*)d_in[0];
  const float* Wk = (const float*)d_in[1];
  const float* Wq = (const float*)d_in[2];
  const float* Wv = (const float*)d_in[3];
  u16* qb = (u16*)d_ws;
  u16* kb = qb + NQ;
  u16* vt = kb + NQ;                 // [8][64][2048] (v transposed)
  u16* wt = vt + NQ;                 // [192][768]
  size_t base = (size_t)(3 * NQ + 192 * CC) * 2;
  auto need = [](int maxnc) {
    return (size_t)128 * maxnc * (8192 * 2 + 1024);
  };
  int CH, CHL;
  if (ws_size >= base + need(8)) { CH = 256; CHL = 8; }
  else if (ws_size >= base + need(4)) { CH = 512; CHL = 9; }
  else { CH = 2048; CHL = 11; }
  int maxnc = 1 << (11 - CHL);
  float* mlb = (float*)((char*)d_ws + base);
  u16* ob = (u16*)((char*)mlb + (size_t)128 * maxnc * 1024);
  float* op = (float*)d_out;

  int nblk = 0;
  for (int qt = 0; qt < 16; ++qt) nblk += (qt * 128 + 128 + CH - 1) >> CHL;
  nblk *= 8;

  hipLaunchKernelGGL(prep_w, dim3(36), dim3(256), 0, stream, Wk, Wq, Wv, wt);
  hipLaunchKernelGGL(qkv_proj, dim3(NBT / 32), dim3(512), 0, stream,
                     x, wt, qb, kb, vt);
  hipLaunchKernelGGL(attn, dim3(nblk), dim3(512), 0, stream,
                     qb, kb, vt, op, mlb, ob, CH, CHL);
  // --- instrumentation: 3 extra attn launches (identical inputs -> identical
  // partials/out; deterministic). dur = base + 3*(attn + gap). Combine runs
  // last and reads the final (identical) partials. ---
  hipLaunchKernelGGL(attn, dim3(nblk), dim3(512), 0, stream,
                     qb, kb, vt, op, mlb, ob, CH, CHL);
  hipLaunchKernelGGL(attn, dim3(nblk), dim3(512), 0, stream,
                     qb, kb, vt, op, mlb, ob, CH, CHL);
  hipLaunchKernelGGL(attn, dim3(nblk), dim3(512), 0, stream,
                     qb, kb, vt, op, mlb, ob, CH, CHL);
  if (CH < 2048)
    hipLaunchKernelGGL(combine, dim3(512), dim3(256), 0, stream,
                       mlb, ob, op, CH, CHL);
}

// Round 16
// 46.273 us; speedup vs baseline: 2.1653x; 2.1653x over previous
//
#include <hip/hip_runtime.h>
#include <hip/hip_bf16.h>
#include <math.h>

typedef float f4 __attribute__((ext_vector_type(4)));
typedef float f32x4 __attribute__((ext_vector_type(4)));
typedef short s8v __attribute__((ext_vector_type(8)));
typedef unsigned short u16;
typedef u16 u16x4 __attribute__((ext_vector_type(4)));
typedef u16 u16x8 __attribute__((ext_vector_type(8)));

#define TT 2048
#define CC 768
#define HH 64
#define NB 8
#define NBT (NB * TT)
#define NQ (NBT * HH)
#define QSCALE 0.18033688011112042f   // 0.125 * log2(e): softmax in base-2

__device__ __forceinline__ u16 f2bf(float f) {
  unsigned u = __float_as_uint(f);
  u = (u + 0x7fffu + ((u >> 16) & 1u)) >> 16;
  return (u16)u;
}
__device__ __forceinline__ float bf2f(u16 v) {
  return __uint_as_float(((unsigned)v) << 16);
}
__device__ __forceinline__ u16x4 pack4(f32x4 v) {
  union { u16x4 u; __hip_bfloat162 h[2]; } r;
  r.h[0] = __float22bfloat162_rn(make_float2(v[0], v[1]));
  r.h[1] = __float22bfloat162_rn(make_float2(v[2], v[3]));
  return r.u;
}
__device__ __forceinline__ s8v pack8(f4 lo, f4 hi) {
  union { s8v s; __hip_bfloat162 h[4]; } r;
  r.h[0] = __float22bfloat162_rn(make_float2(lo.x, lo.y));
  r.h[1] = __float22bfloat162_rn(make_float2(lo.z, lo.w));
  r.h[2] = __float22bfloat162_rn(make_float2(hi.x, hi.y));
  r.h[3] = __float22bfloat162_rn(make_float2(hi.z, hi.w));
  return r.s;
}

#define MFMA16(a, b, c) __builtin_amdgcn_mfma_f32_16x16x32_bf16(a, b, c, 0, 0, 0)

// ---------------------------------------------------------------------------
// Kernel 0: W -> bf16 transposed via LDS tile transpose. wt[c][kc],
// c: 0..63 q, 64..127 k, 128..191 v.
// ---------------------------------------------------------------------------
__global__ __launch_bounds__(256) void prep_w(
    const float* __restrict__ Wk, const float* __restrict__ Wq,
    const float* __restrict__ Wv, u16* __restrict__ wt) {
  __shared__ float ls[64][72];
  const int tid = threadIdx.x;
  const int m = blockIdx.x / 12, kt = blockIdx.x % 12, k0 = kt * 64;
  const float* Wm = (m == 0) ? Wq : (m == 1) ? Wk : Wv;
#pragma unroll
  for (int p = 0; p < 4; ++p) {
    int k = p * 16 + (tid >> 4), h4 = (tid & 15) * 4;
    f4 v = *(const f4*)(Wm + (size_t)(k0 + k) * HH + h4);
    *(f4*)&ls[k][h4] = v;
  }
  __syncthreads();
#pragma unroll
  for (int p = 0; p < 2; ++p) {
    int c = p * 32 + (tid >> 3), slot = tid & 7;
    u16x8 o;
#pragma unroll
    for (int j = 0; j < 8; ++j) o[j] = f2bf(ls[slot * 8 + j][c]);
    *(u16x8*)(wt + (size_t)(m * 64 + c) * CC + k0 + slot * 8) = o;
  }
}

// ---------------------------------------------------------------------------
// Kernel 1: QKV projection (R14-proven, byte-identical). 512 threads (8
// waves: 2 row-groups x 4 col-groups, 3 accs/wave), 16 waves/CU.
// x and W staged via global_load_lds (pre-swizzled source, linear dest).
// LDS: x 2x8KB @0, W 2x24KB @16384.
// ---------------------------------------------------------------------------
__global__ __launch_bounds__(512) void qkv_proj(
    const float* __restrict__ x, const u16* __restrict__ wt,
    u16* __restrict__ qb, u16* __restrict__ kb, u16* __restrict__ vt) {
  __shared__ char lds[65536];
  const int tid = threadIdx.x;
  const int w = tid >> 6, lane = tid & 63;
  const int g = lane >> 4, t16 = lane & 15;
  const int rg = w >> 2, cg = w & 3;
  const int row0 = blockIdx.x * 32;

  auto stage = [&](int buf, int kt) {   // 4 gload_lds per thread
    const int k0 = kt * 64;
    {  // x tile: 512 16B-units, 1 per thread
      int row = tid >> 4;
      int logical = ((tid & 15) * 16) ^ ((row & 7) << 5);
      const float* src = x + (size_t)(row0 + row) * CC + k0 + (logical >> 2);
      char* dst = lds + buf * 8192 + tid * 16;
      __builtin_amdgcn_global_load_lds((const unsigned int*)src,
                                       (unsigned int*)dst, 16, 0, 0);
    }
#pragma unroll
    for (int n = 0; n < 3; ++n) {       // W tile: 1536 units, 3 per thread
      int u = n * 512 + tid;
      int col = u >> 3;
      int logical = ((u & 7) * 16) ^ ((col & 7) << 4);
      const u16* src = wt + (size_t)col * CC + k0 + (logical >> 1);
      char* dst = lds + 16384 + buf * 24576 + n * 8192 + tid * 16;
      __builtin_amdgcn_global_load_lds((const unsigned int*)src,
                                       (unsigned int*)dst, 16, 0, 0);
    }
  };

  f32x4 zz = {0.f, 0.f, 0.f, 0.f};
  f32x4 acc[3];
#pragma unroll
  for (int cf = 0; cf < 3; ++cf) acc[cf] = zz;

  stage(0, 0);
  asm volatile("s_waitcnt vmcnt(0)" ::: "memory");
  __syncthreads();

  for (int kt = 0; kt < 12; ++kt) {
    const int buf = kt & 1;
    if (kt < 11) stage(buf ^ 1, kt + 1);

    const int row = rg * 16 + t16;
    s8v a[2];
#pragma unroll
    for (int ks = 0; ks < 2; ++ks) {
      int off = buf * 8192 + row * 256 +
                ((ks * 128 + g * 32) ^ ((row & 7) << 5));
      f4 lo = *(const f4*)(lds + off);
      f4 hi = *(const f4*)(lds + off + 16);
      a[ks] = pack8(lo, hi);
    }
#pragma unroll
    for (int cf = 0; cf < 3; ++cf) {
      int col = cg * 48 + cf * 16 + t16;
      int wo = 16384 + buf * 24576 + col * 128;
#pragma unroll
      for (int ks = 0; ks < 2; ++ks) {
        s8v b = *(const s8v*)(lds + wo +
                              ((ks * 64 + g * 16) ^ ((col & 7) << 4)));
        acc[cf] = MFMA16(a[ks], b, acc[cf]);
      }
    }

    asm volatile("s_waitcnt vmcnt(0)" ::: "memory");
    __syncthreads();
  }

  // epilogue: D row = g*4+r, col = t16 (m89-verified layout)
  const int rb = row0 + rg * 16 + g * 4;
#pragma unroll
  for (int cf = 0; cf < 3; ++cf) {
    int col = cg * 48 + cf * 16 + t16;
    int m = col >> 6, h = col & 63;
    if (m == 0) {
#pragma unroll
      for (int r = 0; r < 4; ++r)
        qb[(size_t)(rb + r) * HH + h] = f2bf(acc[cf][r] * QSCALE);
    } else if (m == 1) {
#pragma unroll
      for (int r = 0; r < 4; ++r)
        kb[(size_t)(rb + r) * HH + h] = f2bf(acc[cf][r]);
    } else {
      int bbi = rb >> 11;
      u16x4 pk = pack4(acc[cf]);
      *(u16x4*)(vt + (size_t)(bbi * 64 + h) * TT + (rb & 2047)) = pk;
    }
  }
}

// ---------------------------------------------------------------------------
// Kernel 2: flash attention — R7 interior, LDS cut 64->48KB for 3 blocks/CU
// (attn measured ~16us at 2 blocks/CU, latency/straggler-bound; +50% TLP).
// K/V DOUBLE-buffered; prefetch issued AFTER the top barrier (buf^1 is free
// exactly then); vmcnt(0) waits only this wave's 2 loads, issued one full
// compute-phase earlier (K/V are L2-resident: batch==XCD under round-robin).
// LDS: K 2x8KB @0, V 2x8KB @16384, P 8x2KB @32768 = 48KB.
// ---------------------------------------------------------------------------
__global__ __launch_bounds__(512) void attn(
    const u16* __restrict__ qb, const u16* __restrict__ kb,
    const u16* __restrict__ vt, float* __restrict__ out,
    float* __restrict__ ml, u16* __restrict__ ob, int CH, int CHL) {
  __shared__ char lds[49152];
  const int tid = threadIdx.x;
  const int w = tid >> 6, lane = tid & 63;
  const int g = lane >> 4, t16 = lane & 15;
  const int bid = blockIdx.x;
  const int b = bid & 7;
  int J = bid >> 3;

  int q = 15;                           // heavy-first job decode
#pragma unroll 16
  for (int i = 0; i < 16; ++i) {
    int nc_q = (q * 128 + 128 + CH - 1) >> CHL;
    if (J < nc_q) break;
    J -= nc_q;
    --q;
  }
  const int qt = q, ch = J;
  const int q0 = qt * 128;
  const int nc = (q0 + 128 + CH - 1) >> CHL;
  const int kv_lo = ch << CHL;
  const int kv_hi = min(kv_lo + CH, q0 + 128);
  const int nt = (kv_hi - kv_lo) >> 6;
  const int q0w = q0 + w * 16;
  const size_t bT = (size_t)b * TT;
  const int wbase = 32768 + w * 2048;

  // Q as B-fragment (pre-scaled): lane col q = q0w+t16
  s8v qf[2];
#pragma unroll
  for (int s = 0; s < 2; ++s)
    qf[s] = *(const s8v*)(qb + (bT + q0w + t16) * HH + s * 32 + g * 8);

  auto stage = [&](int buf, int kv0) {
    int row = tid >> 3, slot = tid & 7;
    int co = (slot ^ (row & 7)) << 3;
    const u16* sK = kb + (bT + kv0 + row) * HH + co;
    const u16* sV = vt + (size_t)(b * 64 + row) * TT + kv0 + co;
    char* dK = lds + buf * 8192 + w * 1024;
    char* dV = lds + 16384 + buf * 8192 + w * 1024;
    __builtin_amdgcn_global_load_lds((const unsigned int*)sK,
                                     (unsigned int*)dK, 16, 0, 0);
    __builtin_amdgcn_global_load_lds((const unsigned int*)sV,
                                     (unsigned int*)dV, 16, 0, 0);
  };

  float m = -INFINITY, l = 0.f;
  f32x4 zz = {0.f, 0.f, 0.f, 0.f};
  f32x4 oa[4] = {zz, zz, zz, zz};

  stage(0, kv_lo);

  for (int t = 0; t < nt; ++t) {
    const int kv0 = kv_lo + t * 64;
    const int buf = t & 1;
    // own stage(t) loads done (issued one compute-phase ago)
    asm volatile("s_waitcnt vmcnt(0)" ::: "memory");
    __syncthreads();   // publishes stage(t); confirms buf^1 free of readers
    if (t + 1 < nt) stage(buf ^ 1, kv0 + 64);

    if (kv0 <= q0w + 15) {              // wave-uniform: skip fully-masked
      f32x4 sa[4] = {zz, zz, zz, zz};
#pragma unroll
      for (int c = 0; c < 4; ++c) {
        int row = c * 16 + t16;
        s8v k0_ = *(const s8v*)(lds + buf * 8192 +
                                ((row * 128 + g * 16) ^ ((row & 7) << 4)));
        s8v k1_ = *(const s8v*)(lds + buf * 8192 +
                                ((row * 128 + 64 + g * 16) ^ ((row & 7) << 4)));
        sa[c] = MFMA16(k0_, qf[0], sa[c]);
        sa[c] = MFMA16(k1_, qf[1], sa[c]);
      }

      if (kv0 + 63 > q0w) {             // diagonal tile: causal mask
#pragma unroll
        for (int c = 0; c < 4; ++c)
#pragma unroll
          for (int r = 0; r < 4; ++r)
            if (kv0 + c * 16 + g * 4 + r > q0w + t16) sa[c][r] = -INFINITY;
      }

      // online softmax (base-2), defer-max THR=8
      f32x4 mm = sa[0];
#pragma unroll
      for (int c = 1; c < 4; ++c)
#pragma unroll
        for (int r = 0; r < 4; ++r) mm[r] = fmaxf(mm[r], sa[c][r]);
      float mx = fmaxf(fmaxf(mm[0], mm[1]), fmaxf(mm[2], mm[3]));
      mx = fmaxf(mx, __shfl_xor(mx, 16));
      mx = fmaxf(mx, __shfl_xor(mx, 32));
      if (!__all(mx <= m + 8.f)) {
        float mn = fmaxf(m, mx);
        float fr = exp2f(m - mn);
        m = mn;
        l *= fr;
#pragma unroll
        for (int c = 0; c < 4; ++c) oa[c] *= fr;
      }
      f32x4 ps = zz;
#pragma unroll
      for (int c = 0; c < 4; ++c)
#pragma unroll
        for (int r = 0; r < 4; ++r) {
          float p = exp2f(sa[c][r] - m);
          sa[c][r] = p;
          ps[r] += p;
        }
      float rs = (ps[0] + ps[1]) + (ps[2] + ps[3]);
      rs += __shfl_xor(rs, 16);
      rs += __shfl_xor(rs, 32);
      l += rs;

      // P -> wave-private LDS (bf16, swizzled)
#pragma unroll
      for (int c = 0; c < 4; ++c) {
        u16x4 pk = pack4(sa[c]);
        int off = wbase + ((t16 * 128 + c * 32 + g * 8) ^ ((t16 & 7) << 4));
        *(u16x4*)(lds + off) = pk;
      }
      // O^T += V^T . P^T
#pragma unroll
      for (int ks = 0; ks < 2; ++ks) {
        int poff = wbase + ((t16 * 128 + ks * 64 + g * 16) ^ ((t16 & 7) << 4));
        s8v pf = *(const s8v*)(lds + poff);
#pragma unroll
        for (int c = 0; c < 4; ++c) {
          int row = c * 16 + t16;
          s8v vf = *(const s8v*)(lds + 16384 + buf * 8192 +
                                 ((row * 128 + ks * 64 + g * 16) ^
                                  ((row & 7) << 4)));
          oa[c] = MFMA16(vf, pf, oa[c]);
        }
      }
    }
  }

  if (nc == 1) {                        // whole causal range: direct write
    float inv = 1.0f / l;
#pragma unroll
    for (int c = 0; c < 4; ++c) {
      f4 st;
#pragma unroll
      for (int r = 0; r < 4; ++r) st[r] = oa[c][r] * inv;
      *(f4*)(out + (bT + q0w + t16) * HH + c * 16 + g * 4) = st;
    }
  } else {                              // partial: m,l + unnormalized O
    int maxnc = 1 << (11 - CHL);
    int slot = (b * 16 + qt) * maxnc + ch;
    if (g == 0) {
      ml[slot * 256 + w * 16 + t16] = m;
      ml[slot * 256 + 128 + w * 16 + t16] = l;
    }
#pragma unroll
    for (int c = 0; c < 4; ++c) {
      u16x4 pk = pack4(oa[c]);
      *(u16x4*)(ob + (size_t)slot * 8192 + (w * 16 + t16) * 64 + c * 16 +
                g * 4) = pk;
    }
  }
}

// ---------------------------------------------------------------------------
// Kernel 3: combine split-KV partials. Thread = (row, 8 h-cols).
// ---------------------------------------------------------------------------
__global__ __launch_bounds__(256) void combine(
    const float* __restrict__ ml, const u16* __restrict__ ob,
    float* __restrict__ out, int CH, int CHL) {
  int gid = blockIdx.x * 256 + threadIdx.x;   // 131072
  int r = gid >> 3, c8 = (gid & 7) << 3;
  int b = r >> 11, qrow = r & 2047, qt = qrow >> 7, qi = qrow & 127;
  int nc = (qt * 128 + 128 + CH - 1) >> CHL;
  if (nc < 2) return;                          // attn wrote these directly
  int maxnc = 1 << (11 - CHL);
  int s0 = (b * 16 + qt) * maxnc;
  float M = -INFINITY;
  for (int ch = 0; ch < nc; ++ch) M = fmaxf(M, ml[(s0 + ch) * 256 + qi]);
  float L = 0.f;
  float o[8] = {0, 0, 0, 0, 0, 0, 0, 0};
  for (int ch = 0; ch < nc; ++ch) {
    float wgt = exp2f(ml[(s0 + ch) * 256 + qi] - M);
    L += ml[(s0 + ch) * 256 + 128 + qi] * wgt;
    const u16x4* src =
        (const u16x4*)(ob + (size_t)(s0 + ch) * 8192 + qi * 64 + c8);
    u16x4 a = src[0], bv = src[1];
#pragma unroll
    for (int j = 0; j < 4; ++j) {
      o[j] += wgt * bf2f(a[j]);
      o[4 + j] += wgt * bf2f(bv[j]);
    }
  }
  float inv = 1.0f / L;
  f4 s1, s2;
#pragma unroll
  for (int j = 0; j < 4; ++j) { s1[j] = o[j] * inv; s2[j] = o[4 + j] * inv; }
  *(f4*)(out + (size_t)r * HH + c8) = s1;
  *(f4*)(out + (size_t)r * HH + c8 + 4) = s2;
}

extern "C" void kernel_launch(void* const* d_in, const int* in_sizes, int n_in,
                              void* d_out, int out_size, void* d_ws, size_t ws_size,
                              hipStream_t stream) {
  (void)in_sizes; (void)n_in; (void)out_size;
  const float* x  = (const float*)d_in[0];
  const float* Wk = (const float*)d_in[1];
  const float* Wq = (const float*)d_in[2];
  const float* Wv = (const float*)d_in[3];
  u16* qb = (u16*)d_ws;
  u16* kb = qb + NQ;
  u16* vt = kb + NQ;                 // [8][64][2048] (v transposed)
  u16* wt = vt + NQ;                 // [192][768]
  size_t base = (size_t)(3 * NQ + 192 * CC) * 2;
  auto need = [](int maxnc) {
    return (size_t)128 * maxnc * (8192 * 2 + 1024);
  };
  int CH, CHL;
  if (ws_size >= base + need(8)) { CH = 256; CHL = 8; }
  else if (ws_size >= base + need(4)) { CH = 512; CHL = 9; }
  else { CH = 2048; CHL = 11; }
  int maxnc = 1 << (11 - CHL);
  float* mlb = (float*)((char*)d_ws + base);
  u16* ob = (u16*)((char*)mlb + (size_t)128 * maxnc * 1024);
  float* op = (float*)d_out;

  int nblk = 0;
  for (int qt = 0; qt < 16; ++qt) nblk += (qt * 128 + 128 + CH - 1) >> CHL;
  nblk *= 8;

  hipLaunchKernelGGL(prep_w, dim3(36), dim3(256), 0, stream, Wk, Wq, Wv, wt);
  hipLaunchKernelGGL(qkv_proj, dim3(NBT / 32), dim3(512), 0, stream,
                     x, wt, qb, kb, vt);
  hipLaunchKernelGGL(attn, dim3(nblk), dim3(512), 0, stream,
                     qb, kb, vt, op, mlb, ob, CH, CHL);
  if (CH < 2048)
    hipLaunchKernelGGL(combine, dim3(512), dim3(256), 0, stream,
                       mlb, ob, op, CH, CHL);
}

// Round 17
// 43.310 us; speedup vs baseline: 2.3134x; 1.0684x over previous
//
#include <hip/hip_runtime.h>
#include <hip/hip_bf16.h>
#include <math.h>

typedef float f4 __attribute__((ext_vector_type(4)));
typedef float f32x4 __attribute__((ext_vector_type(4)));
typedef short s8v __attribute__((ext_vector_type(8)));
typedef unsigned short u16;
typedef u16 u16x4 __attribute__((ext_vector_type(4)));
typedef u16 u16x8 __attribute__((ext_vector_type(8)));

#define TT 2048
#define CC 768
#define HH 64
#define NB 8
#define NBT (NB * TT)
#define NQ (NBT * HH)
#define QSCALE 0.18033688011112042f   // 0.125 * log2(e): softmax in base-2

__device__ __forceinline__ u16 f2bf(float f) {
  unsigned u = __float_as_uint(f);
  u = (u + 0x7fffu + ((u >> 16) & 1u)) >> 16;
  return (u16)u;
}
__device__ __forceinline__ float bf2f(u16 v) {
  return __uint_as_float(((unsigned)v) << 16);
}
__device__ __forceinline__ u16x4 pack4(f32x4 v) {
  union { u16x4 u; __hip_bfloat162 h[2]; } r;
  r.h[0] = __float22bfloat162_rn(make_float2(v[0], v[1]));
  r.h[1] = __float22bfloat162_rn(make_float2(v[2], v[3]));
  return r.u;
}
__device__ __forceinline__ s8v pack8(f4 lo, f4 hi) {
  union { s8v s; __hip_bfloat162 h[4]; } r;
  r.h[0] = __float22bfloat162_rn(make_float2(lo.x, lo.y));
  r.h[1] = __float22bfloat162_rn(make_float2(lo.z, lo.w));
  r.h[2] = __float22bfloat162_rn(make_float2(hi.x, hi.y));
  r.h[3] = __float22bfloat162_rn(make_float2(hi.z, hi.w));
  return r.s;
}

#define MFMA16(a, b, c) __builtin_amdgcn_mfma_f32_16x16x32_bf16(a, b, c, 0, 0, 0)

// ---------------------------------------------------------------------------
// Kernel 0: W -> bf16 transposed via LDS tile transpose. wt[c][kc],
// c: 0..63 q, 64..127 k, 128..191 v.
// ---------------------------------------------------------------------------
__global__ __launch_bounds__(256) void prep_w(
    const float* __restrict__ Wk, const float* __restrict__ Wq,
    const float* __restrict__ Wv, u16* __restrict__ wt) {
  __shared__ float ls[64][72];
  const int tid = threadIdx.x;
  const int m = blockIdx.x / 12, kt = blockIdx.x % 12, k0 = kt * 64;
  const float* Wm = (m == 0) ? Wq : (m == 1) ? Wk : Wv;
#pragma unroll
  for (int p = 0; p < 4; ++p) {
    int k = p * 16 + (tid >> 4), h4 = (tid & 15) * 4;
    f4 v = *(const f4*)(Wm + (size_t)(k0 + k) * HH + h4);
    *(f4*)&ls[k][h4] = v;
  }
  __syncthreads();
#pragma unroll
  for (int p = 0; p < 2; ++p) {
    int c = p * 32 + (tid >> 3), slot = tid & 7;
    u16x8 o;
#pragma unroll
    for (int j = 0; j < 8; ++j) o[j] = f2bf(ls[slot * 8 + j][c]);
    *(u16x8*)(wt + (size_t)(m * 64 + c) * CC + k0 + slot * 8) = o;
  }
}

// ---------------------------------------------------------------------------
// Kernel 1: QKV projection (R14-proven, byte-identical). 512 threads (8
// waves: 2 row-groups x 4 col-groups, 3 accs/wave), 16 waves/CU.
// x and W staged via global_load_lds (pre-swizzled source, linear dest).
// LDS: x 2x8KB @0, W 2x24KB @16384.
// ---------------------------------------------------------------------------
__global__ __launch_bounds__(512) void qkv_proj(
    const float* __restrict__ x, const u16* __restrict__ wt,
    u16* __restrict__ qb, u16* __restrict__ kb, u16* __restrict__ vt) {
  __shared__ char lds[65536];
  const int tid = threadIdx.x;
  const int w = tid >> 6, lane = tid & 63;
  const int g = lane >> 4, t16 = lane & 15;
  const int rg = w >> 2, cg = w & 3;
  const int row0 = blockIdx.x * 32;

  auto stage = [&](int buf, int kt) {   // 4 gload_lds per thread
    const int k0 = kt * 64;
    {  // x tile: 512 16B-units, 1 per thread
      int row = tid >> 4;
      int logical = ((tid & 15) * 16) ^ ((row & 7) << 5);
      const float* src = x + (size_t)(row0 + row) * CC + k0 + (logical >> 2);
      char* dst = lds + buf * 8192 + tid * 16;
      __builtin_amdgcn_global_load_lds((const unsigned int*)src,
                                       (unsigned int*)dst, 16, 0, 0);
    }
#pragma unroll
    for (int n = 0; n < 3; ++n) {       // W tile: 1536 units, 3 per thread
      int u = n * 512 + tid;
      int col = u >> 3;
      int logical = ((u & 7) * 16) ^ ((col & 7) << 4);
      const u16* src = wt + (size_t)col * CC + k0 + (logical >> 1);
      char* dst = lds + 16384 + buf * 24576 + n * 8192 + tid * 16;
      __builtin_amdgcn_global_load_lds((const unsigned int*)src,
                                       (unsigned int*)dst, 16, 0, 0);
    }
  };

  f32x4 zz = {0.f, 0.f, 0.f, 0.f};
  f32x4 acc[3];
#pragma unroll
  for (int cf = 0; cf < 3; ++cf) acc[cf] = zz;

  stage(0, 0);
  asm volatile("s_waitcnt vmcnt(0)" ::: "memory");
  __syncthreads();

  for (int kt = 0; kt < 12; ++kt) {
    const int buf = kt & 1;
    if (kt < 11) stage(buf ^ 1, kt + 1);

    const int row = rg * 16 + t16;
    s8v a[2];
#pragma unroll
    for (int ks = 0; ks < 2; ++ks) {
      int off = buf * 8192 + row * 256 +
                ((ks * 128 + g * 32) ^ ((row & 7) << 5));
      f4 lo = *(const f4*)(lds + off);
      f4 hi = *(const f4*)(lds + off + 16);
      a[ks] = pack8(lo, hi);
    }
#pragma unroll
    for (int cf = 0; cf < 3; ++cf) {
      int col = cg * 48 + cf * 16 + t16;
      int wo = 16384 + buf * 24576 + col * 128;
#pragma unroll
      for (int ks = 0; ks < 2; ++ks) {
        s8v b = *(const s8v*)(lds + wo +
                              ((ks * 64 + g * 16) ^ ((col & 7) << 4)));
        acc[cf] = MFMA16(a[ks], b, acc[cf]);
      }
    }

    asm volatile("s_waitcnt vmcnt(0)" ::: "memory");
    __syncthreads();
  }

  // epilogue: D row = g*4+r, col = t16 (m89-verified layout)
  const int rb = row0 + rg * 16 + g * 4;
#pragma unroll
  for (int cf = 0; cf < 3; ++cf) {
    int col = cg * 48 + cf * 16 + t16;
    int m = col >> 6, h = col & 63;
    if (m == 0) {
#pragma unroll
      for (int r = 0; r < 4; ++r)
        qb[(size_t)(rb + r) * HH + h] = f2bf(acc[cf][r] * QSCALE);
    } else if (m == 1) {
#pragma unroll
      for (int r = 0; r < 4; ++r)
        kb[(size_t)(rb + r) * HH + h] = f2bf(acc[cf][r]);
    } else {
      int bbi = rb >> 11;
      u16x4 pk = pack4(acc[cf]);
      *(u16x4*)(vt + (size_t)(bbi * 64 + h) * TT + (rb & 2047)) = pk;
    }
  }
}

// ---------------------------------------------------------------------------
// Kernel 2: flash attention (R16, byte-identical). 8 waves/block, Q-block 128
// rows (wave=16 rows, swapped QK^T: lane owns q-row). K/V double-buffered,
// prefetch after top barrier. Defer-max THR=8.
// LDS: K 2x8KB @0, V 2x8KB @16384, P 8x2KB @32768 = 48KB.
// ---------------------------------------------------------------------------
__global__ __launch_bounds__(512) void attn(
    const u16* __restrict__ qb, const u16* __restrict__ kb,
    const u16* __restrict__ vt, float* __restrict__ out,
    float* __restrict__ ml, u16* __restrict__ ob, int CH, int CHL) {
  __shared__ char lds[49152];
  const int tid = threadIdx.x;
  const int w = tid >> 6, lane = tid & 63;
  const int g = lane >> 4, t16 = lane & 15;
  const int bid = blockIdx.x;
  const int b = bid & 7;
  int J = bid >> 3;

  int q = 15;                           // heavy-first job decode
#pragma unroll 16
  for (int i = 0; i < 16; ++i) {
    int nc_q = (q * 128 + 128 + CH - 1) >> CHL;
    if (J < nc_q) break;
    J -= nc_q;
    --q;
  }
  const int qt = q, ch = J;
  const int q0 = qt * 128;
  const int nc = (q0 + 128 + CH - 1) >> CHL;
  const int kv_lo = ch << CHL;
  const int kv_hi = min(kv_lo + CH, q0 + 128);
  const int nt = (kv_hi - kv_lo) >> 6;
  const int q0w = q0 + w * 16;
  const size_t bT = (size_t)b * TT;
  const int wbase = 32768 + w * 2048;

  // Q as B-fragment (pre-scaled): lane col q = q0w+t16
  s8v qf[2];
#pragma unroll
  for (int s = 0; s < 2; ++s)
    qf[s] = *(const s8v*)(qb + (bT + q0w + t16) * HH + s * 32 + g * 8);

  auto stage = [&](int buf, int kv0) {
    int row = tid >> 3, slot = tid & 7;
    int co = (slot ^ (row & 7)) << 3;
    const u16* sK = kb + (bT + kv0 + row) * HH + co;
    const u16* sV = vt + (size_t)(b * 64 + row) * TT + kv0 + co;
    char* dK = lds + buf * 8192 + w * 1024;
    char* dV = lds + 16384 + buf * 8192 + w * 1024;
    __builtin_amdgcn_global_load_lds((const unsigned int*)sK,
                                     (unsigned int*)dK, 16, 0, 0);
    __builtin_amdgcn_global_load_lds((const unsigned int*)sV,
                                     (unsigned int*)dV, 16, 0, 0);
  };

  float m = -INFINITY, l = 0.f;
  f32x4 zz = {0.f, 0.f, 0.f, 0.f};
  f32x4 oa[4] = {zz, zz, zz, zz};

  stage(0, kv_lo);

  for (int t = 0; t < nt; ++t) {
    const int kv0 = kv_lo + t * 64;
    const int buf = t & 1;
    asm volatile("s_waitcnt vmcnt(0)" ::: "memory");
    __syncthreads();   // publishes stage(t); confirms buf^1 free of readers
    if (t + 1 < nt) stage(buf ^ 1, kv0 + 64);

    if (kv0 <= q0w + 15) {              // wave-uniform: skip fully-masked
      f32x4 sa[4] = {zz, zz, zz, zz};
#pragma unroll
      for (int c = 0; c < 4; ++c) {
        int row = c * 16 + t16;
        s8v k0_ = *(const s8v*)(lds + buf * 8192 +
                                ((row * 128 + g * 16) ^ ((row & 7) << 4)));
        s8v k1_ = *(const s8v*)(lds + buf * 8192 +
                                ((row * 128 + 64 + g * 16) ^ ((row & 7) << 4)));
        sa[c] = MFMA16(k0_, qf[0], sa[c]);
        sa[c] = MFMA16(k1_, qf[1], sa[c]);
      }

      if (kv0 + 63 > q0w) {             // diagonal tile: causal mask
#pragma unroll
        for (int c = 0; c < 4; ++c)
#pragma unroll
          for (int r = 0; r < 4; ++r)
            if (kv0 + c * 16 + g * 4 + r > q0w + t16) sa[c][r] = -INFINITY;
      }

      // online softmax (base-2), defer-max THR=8
      f32x4 mm = sa[0];
#pragma unroll
      for (int c = 1; c < 4; ++c)
#pragma unroll
        for (int r = 0; r < 4; ++r) mm[r] = fmaxf(mm[r], sa[c][r]);
      float mx = fmaxf(fmaxf(mm[0], mm[1]), fmaxf(mm[2], mm[3]));
      mx = fmaxf(mx, __shfl_xor(mx, 16));
      mx = fmaxf(mx, __shfl_xor(mx, 32));
      if (!__all(mx <= m + 8.f)) {
        float mn = fmaxf(m, mx);
        float fr = exp2f(m - mn);
        m = mn;
        l *= fr;
#pragma unroll
        for (int c = 0; c < 4; ++c) oa[c] *= fr;
      }
      f32x4 ps = zz;
#pragma unroll
      for (int c = 0; c < 4; ++c)
#pragma unroll
        for (int r = 0; r < 4; ++r) {
          float p = exp2f(sa[c][r] - m);
          sa[c][r] = p;
          ps[r] += p;
        }
      float rs = (ps[0] + ps[1]) + (ps[2] + ps[3]);
      rs += __shfl_xor(rs, 16);
      rs += __shfl_xor(rs, 32);
      l += rs;

      // P -> wave-private LDS (bf16, swizzled)
#pragma unroll
      for (int c = 0; c < 4; ++c) {
        u16x4 pk = pack4(sa[c]);
        int off = wbase + ((t16 * 128 + c * 32 + g * 8) ^ ((t16 & 7) << 4));
        *(u16x4*)(lds + off) = pk;
      }
      // O^T += V^T . P^T
#pragma unroll
      for (int ks = 0; ks < 2; ++ks) {
        int poff = wbase + ((t16 * 128 + ks * 64 + g * 16) ^ ((t16 & 7) << 4));
        s8v pf = *(const s8v*)(lds + poff);
#pragma unroll
        for (int c = 0; c < 4; ++c) {
          int row = c * 16 + t16;
          s8v vf = *(const s8v*)(lds + 16384 + buf * 8192 +
                                 ((row * 128 + ks * 64 + g * 16) ^
                                  ((row & 7) << 4)));
          oa[c] = MFMA16(vf, pf, oa[c]);
        }
      }
    }
  }

  if (nc == 1) {                        // whole causal range: direct write
    float inv = 1.0f / l;
#pragma unroll
    for (int c = 0; c < 4; ++c) {
      f4 st;
#pragma unroll
      for (int r = 0; r < 4; ++r) st[r] = oa[c][r] * inv;
      *(f4*)(out + (bT + q0w + t16) * HH + c * 16 + g * 4) = st;
    }
  } else {                              // partial: m,l + unnormalized O
    int maxnc = 1 << (11 - CHL);
    int slot = (b * 16 + qt) * maxnc + ch;
    if (g == 0) {
      ml[slot * 256 + w * 16 + t16] = m;
      ml[slot * 256 + 128 + w * 16 + t16] = l;
    }
#pragma unroll
    for (int c = 0; c < 4; ++c) {
      u16x4 pk = pack4(oa[c]);
      *(u16x4*)(ob + (size_t)slot * 8192 + (w * 16 + t16) * 64 + c * 16 +
                g * 4) = pk;
    }
  }
}

// ---------------------------------------------------------------------------
// Kernel 3: combine split-KV partials — LATENCY-PIPELINED rewrite.
// All ml (16 scalars) and ob (8 x 16B) loads issued UP FRONT via static
// unroll to maxnc=8 with wave-uniform ch<nc guards (qt uniform across each
// wave's 8 rows); single vmcnt drain replaces up to 8 serial dependent
// round-trips x 2 passes. ml read once into registers.
// ---------------------------------------------------------------------------
__global__ __launch_bounds__(256) void combine(
    const float* __restrict__ ml, const u16* __restrict__ ob,
    float* __restrict__ out, int CH, int CHL) {
  int gid = blockIdx.x * 256 + threadIdx.x;   // 131072
  int r = gid >> 3, c8 = (gid & 7) << 3;
  int b = r >> 11, qrow = r & 2047, qt = qrow >> 7, qi = qrow & 127;
  int nc = (qt * 128 + 128 + CH - 1) >> CHL;
  if (nc < 2) return;                          // attn wrote these directly
  int maxnc = 1 << (11 - CHL);
  int s0 = (b * 16 + qt) * maxnc;

  // issue ALL loads up front (independent addresses; compiler pipelines)
  float mv[8], lv[8];
  u16x8 pv[8];
#pragma unroll
  for (int ch = 0; ch < 8; ++ch) {
    if (ch < nc) {                       // wave-uniform guard
      const float* mlp = ml + (size_t)(s0 + ch) * 256;
      mv[ch] = mlp[qi];
      lv[ch] = mlp[128 + qi];
      pv[ch] = *(const u16x8*)(ob + (size_t)(s0 + ch) * 8192 + qi * 64 + c8);
    } else {
      mv[ch] = -INFINITY;
      lv[ch] = 0.f;
    }
  }

  float M = -INFINITY;
#pragma unroll
  for (int ch = 0; ch < 8; ++ch) M = fmaxf(M, mv[ch]);

  float L = 0.f;
  float o[8] = {0, 0, 0, 0, 0, 0, 0, 0};
#pragma unroll
  for (int ch = 0; ch < 8; ++ch) {
    if (ch < nc) {
      float wgt = exp2f(mv[ch] - M);
      L += lv[ch] * wgt;
#pragma unroll
      for (int j = 0; j < 8; ++j) o[j] += wgt * bf2f(pv[ch][j]);
    }
  }
  float inv = 1.0f / L;
  f4 s1, s2;
#pragma unroll
  for (int j = 0; j < 4; ++j) { s1[j] = o[j] * inv; s2[j] = o[4 + j] * inv; }
  *(f4*)(out + (size_t)r * HH + c8) = s1;
  *(f4*)(out + (size_t)r * HH + c8 + 4) = s2;
}

extern "C" void kernel_launch(void* const* d_in, const int* in_sizes, int n_in,
                              void* d_out, int out_size, void* d_ws, size_t ws_size,
                              hipStream_t stream) {
  (void)in_sizes; (void)n_in; (void)out_size;
  const float* x  = (const float*)d_in[0];
  const float* Wk = (const float*)d_in[1];
  const float* Wq = (const float*)d_in[2];
  const float* Wv = (const float*)d_in[3];
  u16* qb = (u16*)d_ws;
  u16* kb = qb + NQ;
  u16* vt = kb + NQ;                 // [8][64][2048] (v transposed)
  u16* wt = vt + NQ;                 // [192][768]
  size_t base = (size_t)(3 * NQ + 192 * CC) * 2;
  auto need = [](int maxnc) {
    return (size_t)128 * maxnc * (8192 * 2 + 1024);
  };
  int CH, CHL;
  if (ws_size >= base + need(8)) { CH = 256; CHL = 8; }
  else if (ws_size >= base + need(4)) { CH = 512; CHL = 9; }
  else { CH = 2048; CHL = 11; }
  int maxnc = 1 << (11 - CHL);
  float* mlb = (float*)((char*)d_ws + base);
  u16* ob = (u16*)((char*)mlb + (size_t)128 * maxnc * 1024);
  float* op = (float*)d_out;

  int nblk = 0;
  for (int qt = 0; qt < 16; ++qt) nblk += (qt * 128 + 128 + CH - 1) >> CHL;
  nblk *= 8;

  hipLaunchKernelGGL(prep_w, dim3(36), dim3(256), 0, stream, Wk, Wq, Wv, wt);
  hipLaunchKernelGGL(qkv_proj, dim3(NBT / 32), dim3(512), 0, stream,
                     x, wt, qb, kb, vt);
  hipLaunchKernelGGL(attn, dim3(nblk), dim3(512), 0, stream,
                     qb, kb, vt, op, mlb, ob, CH, CHL);
  if (CH < 2048)
    hipLaunchKernelGGL(combine, dim3(512), dim3(256), 0, stream,
                       mlb, ob, op, CH, CHL);
}